// Round 11
// baseline (210.389 us; speedup 1.0000x reference)
//
#include <hip/hip_runtime.h>
#include <hip/hip_bf16.h>

#define B 4
#define S 2048
#define H 16
#define D 64
#define HID 1024

typedef __hip_bfloat16 bf16;
typedef __attribute__((ext_vector_type(8))) short bf16x8;
typedef __attribute__((ext_vector_type(4))) short bf16x4;
typedef __attribute__((ext_vector_type(4))) float f32x4;

static __device__ __forceinline__ float b2f(bf16 v) { return __bfloat162float(v); }

// runtime-dtype scalar load (flag=1 -> fp32 buffer)
static __device__ __forceinline__ float ldx(const void* p, size_t i, int f) {
    return f ? ((const float*)p)[i] : b2f(((const bf16*)p)[i]);
}

static __device__ __forceinline__ unsigned pkbf(float a, float b) {
    union { bf16 h; unsigned short u; } ua, ub;
    ua.h = __float2bfloat16(a);
    ub.h = __float2bfloat16(b);
    return (unsigned)ua.u | ((unsigned)ub.u << 16);
}

// ---------------------------------------------------------------------------
// Kernel 0: dtype detector (proven R2-R10). flags[i]=1 -> fp32.
// ---------------------------------------------------------------------------
__global__ __launch_bounds__(256) void detect_kernel(
    const void* p0, const void* p1, const void* p2, const void* p3,
    const void* p4, const void* p5, const void* p6, const void* p7,
    const void* p8, int* flags)
{
    __shared__ int cnt;
    const void* ps[9] = {p0, p1, p2, p3, p4, p5, p6, p7, p8};
    const int   ns[9] = {B * S * D, D * HID, HID, D * HID, HID,
                         D * HID, HID, HID * D, D};
    const int i = blockIdx.x;
    const bf16* p = (const bf16*)ps[i];
    int n = ns[i];
    if (n > 2048) n = 2048;
    if (threadIdx.x == 0) cnt = 0;
    __syncthreads();
    int wild = 0;
    for (int t = threadIdx.x; t < n; t += 256) {
        float f = b2f(p[t]);
        if (!(f == f) || fabsf(f) > 1e4f) wild++;
    }
    if (wild) atomicAdd(&cnt, wild);
    __syncthreads();
    if (threadIdx.x == 0) flags[i] = (cnt >= 2) ? 1 : 0;
}

// ---------------------------------------------------------------------------
// Kernel 0b: one-shot bf16 pre-convert: xb[8192x64], WtA[3][1024][64] (=W^T),
// WoT[64][1024] (=Wo^T). Makes all downstream staging pure b128 vector loads.
// ---------------------------------------------------------------------------
__global__ __launch_bounds__(256) void prep_kernel(
    const void* x, const void* Wq, const void* Wk, const void* Wv,
    const void* Wo, bf16* xb, bf16* WtA, bf16* WoT, const int* flags)
{
    const int idx = blockIdx.x * 256 + threadIdx.x;
    if (idx < 524288) {                       // xb
        xb[idx] = __float2bfloat16(ldx(x, idx, flags[0]));
    } else if (idx < 720896) {                // WtA[mat][n][k] = W[k][n]
        int t = idx - 524288;
        int mat = t >> 16, r = t & 65535;
        int n = r >> 6, k = r & 63;
        const void* W = (mat == 0) ? Wq : (mat == 1) ? Wk : Wv;
        int f = flags[1 + 2 * mat];
        WtA[t] = __float2bfloat16(ldx(W, (size_t)k * HID + n, f));
    } else if (idx < 786432) {                // WoT[n][k] = Wo[k][n]
        int t = idx - 720896;
        int n = t >> 10, k = t & 1023;
        WoT[t] = __float2bfloat16(ldx(Wo, (size_t)k * 64 + n, flags[7]));
    }
}

// ---------------------------------------------------------------------------
// Kernel 1: QKV projection as MFMA GEMM, all-bf16 staging (from prep).
// Q,K stored [B][H][S][D]; V stored TRANSPOSED [B][H][D][S].
// ---------------------------------------------------------------------------
#define QSTR 72

__global__ __launch_bounds__(256) void qkv_mfma_kernel(
    const bf16* __restrict__ xb, const bf16* __restrict__ WtA,
    const void* bq, const void* bk, const void* bv,
    bf16* __restrict__ q, bf16* __restrict__ k, bf16* __restrict__ v,
    const int* __restrict__ flags)
{
    __shared__ bf16 Xs[128 * QSTR];
    __shared__ bf16 Wt[128 * QSTR];
    __shared__ float bs[128];

    const int tid = threadIdx.x;
    const int mat = blockIdx.y >> 3;
    const int N0  = (blockIdx.y & 7) * 128;
    const int m0  = blockIdx.x * 128;

    const void* bias = (mat == 0) ? bq : (mat == 1) ? bk : bv;
    const int   bfl  = flags[2 + 2 * mat];
    bf16*       dst  = (mat == 0) ? q  : (mat == 1) ? k  : v;
    const bf16* Wsrc = WtA + (size_t)mat * HID * 64;

    // ---- stage x tile and W^T tile: pure b128 vector loads ----
    #pragma unroll
    for (int i = 0; i < 4; ++i) {
        int item = i * 256 + tid;              // 0..1023: row*8 + oct
        int row = item >> 3, oct = item & 7;
        *(bf16x8*)&Xs[row * QSTR + oct * 8] =
            *(const bf16x8*)(xb + (size_t)(m0 + row) * D + oct * 8);
        *(bf16x8*)&Wt[row * QSTR + oct * 8] =
            *(const bf16x8*)(Wsrc + (size_t)(N0 + row) * 64 + oct * 8);
    }
    if (tid < 128) bs[tid] = ldx(bias, N0 + tid, bfl);
    __syncthreads();

    const int lane = tid & 63, wave = tid >> 6;
    const int c = lane & 15, quad = lane >> 4;

    bf16x8 af[2][2];
    #pragma unroll
    for (int mg = 0; mg < 2; ++mg)
        #pragma unroll
        for (int kc = 0; kc < 2; ++kc)
            af[mg][kc] = *(const bf16x8*)&Xs[(wave * 32 + mg * 16 + c) * QSTR + kc * 32 + quad * 8];

    f32x4 acc[2][8];
    #pragma unroll
    for (int mg = 0; mg < 2; ++mg)
        #pragma unroll
        for (int ng = 0; ng < 8; ++ng)
            acc[mg][ng] = (f32x4){0.f, 0.f, 0.f, 0.f};

    #pragma unroll
    for (int ng = 0; ng < 8; ++ng) {
        bf16x8 bf0 = *(const bf16x8*)&Wt[(ng * 16 + c) * QSTR + quad * 8];
        bf16x8 bf1 = *(const bf16x8*)&Wt[(ng * 16 + c) * QSTR + 32 + quad * 8];
        #pragma unroll
        for (int mg = 0; mg < 2; ++mg) {
            acc[mg][ng] = __builtin_amdgcn_mfma_f32_16x16x32_bf16(af[mg][0], bf0, acc[mg][ng], 0, 0, 0);
            acc[mg][ng] = __builtin_amdgcn_mfma_f32_16x16x32_bf16(af[mg][1], bf1, acc[mg][ng], 0, 0, 0);
        }
    }

    if (mat == 2) {
        // V: transposed store [B][H][D][S]; 4 consecutive ss -> 8B store
        #pragma unroll
        for (int ng = 0; ng < 8; ++ng) {
            int n_g = N0 + ng * 16 + c;
            int h = n_g >> 6, dd = n_g & 63;
            float bb_ = bs[ng * 16 + c];
            #pragma unroll
            for (int mg = 0; mg < 2; ++mg) {
                int row0 = m0 + wave * 32 + mg * 16 + quad * 4;
                int b_ = row0 >> 11, ss = row0 & (S - 1);
                union { bf16 h4[4]; bf16x4 v4; } u;
                #pragma unroll
                for (int r = 0; r < 4; ++r)
                    u.h4[r] = __float2bfloat16(acc[mg][ng][r] + bb_);
                *(bf16x4*)&dst[((size_t)(b_ * H + h) * D + dd) * S + ss] = u.v4;
            }
        }
    } else {
        #pragma unroll
        for (int ng = 0; ng < 8; ++ng) {
            int n_g = N0 + ng * 16 + c;
            int h = n_g >> 6, dd = n_g & 63;
            float bb_ = bs[ng * 16 + c];
            #pragma unroll
            for (int mg = 0; mg < 2; ++mg) {
                #pragma unroll
                for (int r = 0; r < 4; ++r) {
                    int row = m0 + wave * 32 + mg * 16 + quad * 4 + r;
                    int b_ = row >> 11, ss = row & (S - 1);
                    dst[((size_t)(b_ * H + h) * S + ss) * D + dd] =
                        __float2bfloat16(acc[mg][ng][r] + bb_);
                }
            }
        }
    }
}

// ---------------------------------------------------------------------------
// Kernel 2: flash causal attention — MERGED-PHASE + XCD swizzle.
//  * One kt loop serves BOTH q-tiles (qt=pair and qt=31-pair): shared K/V
//    staging prefix -> 33 -> (32-pair) iterations/block (-26% staging).
//  * XCD swizzle: L%8 = XCD; each XCD owns 8 heads -> K/V set = 4MB = L2.
//  * R10 core: S^T=K.Q^T per-lane softmax, P^T wave-private LDS, O^T=V^T.P^T.
//  * Work variance 1.9:1 max (vs R6's fatal 32:1), pair varies fastest in
//    dispatch order -> mixed durations per CU, self-balancing refill.
// ---------------------------------------------------------------------------
#define BT   64
#define NT   (S / BT)   // 32
#define KSTR 72
#define PST  72
#define MNEG -30000.0f
#define SCL  0.18033688011112042f   // 0.125 * log2(e)

__global__ __launch_bounds__(256) void flash_mfma_kernel(
    const bf16* __restrict__ qg, const bf16* __restrict__ kg,
    const bf16* __restrict__ vg, bf16* __restrict__ og)
{
    __shared__ bf16 Ks[BT * KSTR];     // K tile [krow][d]
    __shared__ bf16 Vt[BT * KSTR];     // V^T tile [d][krow]
    __shared__ bf16 Ps[4][16 * PST];   // per-wave P [qrow c][kcol]

    const int tid  = threadIdx.x;
    const int wave = tid >> 6;
    const int lane = tid & 63;
    const int c    = lane & 15;
    const int quad = lane >> 4;

    const int L    = (int)blockIdx.x + 16 * (int)blockIdx.y;  // 0..1023
    const int xcd  = L & 7;
    const int slot = L >> 3;            // 0..127
    const int pair = slot & 15;         // fast-varying -> mixed durations/CU
    const int bh   = xcd * 8 + (slot >> 4);
    const int b_   = bh >> 4, h_ = bh & 15;
    const size_t hbase = (size_t)bh * S * D;
    bf16* myPs = &Ps[wave][0];
    const int srow = wave * 16 + c;

    const int qta = pair;               // light tile
    const int qtb = NT - 1 - pair;      // heavy tile (drives the loop)

    const int sr0 = tid >> 3,         sc0 = (tid & 7) * 8;
    const int sr1 = (tid + 256) >> 3, sc1 = sc0;

    // Q fragments for both tiles
    bf16x8 qfa0, qfa1, qfb0, qfb1;
    {
        const size_t ra = hbase + (size_t)(qta * BT + srow) * D;
        const size_t rb = hbase + (size_t)(qtb * BT + srow) * D;
        qfa0 = *(const bf16x8*)(qg + ra + quad * 8);
        qfa1 = *(const bf16x8*)(qg + ra + 32 + quad * 8);
        qfb0 = *(const bf16x8*)(qg + rb + quad * 8);
        qfb1 = *(const bf16x8*)(qg + rb + 32 + quad * 8);
    }

    // prefetch tile 0
    bf16x8 kreg0, kreg1, vreg0, vreg1;
    kreg0 = *(const bf16x8*)(kg + hbase + (size_t)sr0 * D + sc0);
    kreg1 = *(const bf16x8*)(kg + hbase + (size_t)sr1 * D + sc1);
    vreg0 = *(const bf16x8*)(vg + hbase + (size_t)sr0 * S + sc0);
    vreg1 = *(const bf16x8*)(vg + hbase + (size_t)sr1 * S + sc1);

    float ma = MNEG, la = 0.f, mb = MNEG, lb = 0.f;
    f32x4 ota[4], otb[4];
    #pragma unroll
    for (int jn = 0; jn < 4; ++jn) {
        ota[jn] = (f32x4){0.f, 0.f, 0.f, 0.f};
        otb[jn] = (f32x4){0.f, 0.f, 0.f, 0.f};
    }

    // one online-softmax + PV step for one tile (R10-verified core)
    auto tile_step = [&](bf16x8 qf0, bf16x8 qf1, f32x4* ot,
                         float& m1, float& l1, bool diag) {
        f32x4 st[4];
        #pragma unroll
        for (int jn = 0; jn < 4; ++jn) {
            bf16x8 kf0 = *(const bf16x8*)&Ks[(jn * 16 + c) * KSTR + quad * 8];
            bf16x8 kf1 = *(const bf16x8*)&Ks[(jn * 16 + c) * KSTR + 32 + quad * 8];
            f32x4 s = {0.f, 0.f, 0.f, 0.f};
            s = __builtin_amdgcn_mfma_f32_16x16x32_bf16(kf0, qf0, s, 0, 0, 0);
            s = __builtin_amdgcn_mfma_f32_16x16x32_bf16(kf1, qf1, s, 0, 0, 0);
            st[jn] = s;
        }
        #pragma unroll
        for (int jn = 0; jn < 4; ++jn)
            #pragma unroll
            for (int r = 0; r < 4; ++r) st[jn][r] *= SCL;
        if (diag) {
            #pragma unroll
            for (int jn = 0; jn < 4; ++jn)
                #pragma unroll
                for (int r = 0; r < 4; ++r)
                    if (jn * 16 + quad * 4 + r > srow) st[jn][r] = MNEG;
        }
        float rm = st[0][0];
        #pragma unroll
        for (int jn = 0; jn < 4; ++jn)
            #pragma unroll
            for (int r = 0; r < 4; ++r) rm = fmaxf(rm, st[jn][r]);
        rm = fmaxf(rm, __shfl_xor(rm, 16));
        rm = fmaxf(rm, __shfl_xor(rm, 32));
        float mn = fmaxf(m1, rm);
        float alpha = __builtin_amdgcn_exp2f(m1 - mn);
        float rs = 0.f;
        uint2 pk[4];
        #pragma unroll
        for (int jn = 0; jn < 4; ++jn) {
            float p0 = __builtin_amdgcn_exp2f(st[jn][0] - mn);
            float p1 = __builtin_amdgcn_exp2f(st[jn][1] - mn);
            float p2 = __builtin_amdgcn_exp2f(st[jn][2] - mn);
            float p3 = __builtin_amdgcn_exp2f(st[jn][3] - mn);
            rs += (p0 + p1) + (p2 + p3);
            pk[jn].x = pkbf(p0, p1);
            pk[jn].y = pkbf(p2, p3);
        }
        rs += __shfl_xor(rs, 16);
        rs += __shfl_xor(rs, 32);
        l1 = l1 * alpha + rs;
        m1 = mn;
        #pragma unroll
        for (int jn = 0; jn < 4; ++jn)
            #pragma unroll
            for (int r = 0; r < 4; ++r) ot[jn][r] *= alpha;

        // WAR guard: prior tile's Ps reads drained before overwrite
        asm volatile("s_waitcnt lgkmcnt(0)" ::: "memory");
        #pragma unroll
        for (int jn = 0; jn < 4; ++jn)
            *(uint2*)&myPs[c * PST + jn * 16 + quad * 4] = pk[jn];
        asm volatile("s_waitcnt lgkmcnt(0)" ::: "memory");

        #pragma unroll
        for (int kc = 0; kc < 2; ++kc) {
            bf16x8 pf = *(const bf16x8*)&myPs[c * PST + kc * 32 + quad * 8];
            #pragma unroll
            for (int jn = 0; jn < 4; ++jn) {
                bf16x8 vf = *(const bf16x8*)&Vt[(jn * 16 + c) * KSTR + kc * 32 + quad * 8];
                ot[jn] = __builtin_amdgcn_mfma_f32_16x16x32_bf16(vf, pf, ot[jn], 0, 0, 0);
            }
        }
    };

    for (int kt = 0; kt <= qtb; ++kt) {
        __syncthreads();   // prior tile's LDS reads complete
        *(bf16x8*)&Ks[sr0 * KSTR + sc0] = kreg0;
        *(bf16x8*)&Ks[sr1 * KSTR + sc1] = kreg1;
        *(bf16x8*)&Vt[sr0 * KSTR + sc0] = vreg0;
        *(bf16x8*)&Vt[sr1 * KSTR + sc1] = vreg1;
        __syncthreads();   // tile visible

        if (kt < qtb) {
            const int nb = (kt + 1) * BT;
            kreg0 = *(const bf16x8*)(kg + hbase + (size_t)(nb + sr0) * D + sc0);
            kreg1 = *(const bf16x8*)(kg + hbase + (size_t)(nb + sr1) * D + sc1);
            vreg0 = *(const bf16x8*)(vg + hbase + (size_t)sr0 * S + nb + sc0);
            vreg1 = *(const bf16x8*)(vg + hbase + (size_t)sr1 * S + nb + sc1);
        }

        tile_step(qfb0, qfb1, otb, mb, lb, kt == qtb);
        if (kt <= qta) tile_step(qfa0, qfa1, ota, ma, la, kt == qta);
    }

    // ---- epilogues: lane owns one q-row; d = 16jn + 4quad + r ----
    auto epilogue = [&](const f32x4* ot, float l1, int qt) {
        const float inv = 1.f / l1;
        const size_t obase = ((size_t)(b_ * S + qt * BT + srow)) * HID + h_ * 64 + quad * 4;
        #pragma unroll
        for (int jn = 0; jn < 4; ++jn) {
            union { bf16 h4[4]; bf16x4 v4; } u;
            #pragma unroll
            for (int r = 0; r < 4; ++r)
                u.h4[r] = __float2bfloat16(ot[jn][r] * inv);
            *(bf16x4*)&og[obase + jn * 16] = u.v4;
        }
    };
    epilogue(otb, lb, qtb);
    epilogue(ota, la, qta);
}

// ---------------------------------------------------------------------------
// Kernel 3: output projection as MFMA GEMM; Wo^T staged bf16 (from prep).
// ---------------------------------------------------------------------------
__global__ __launch_bounds__(256) void out_proj_mfma_kernel(
    const bf16* __restrict__ o, const bf16* __restrict__ WoT,
    const void* bo, void* __restrict__ out, const int* __restrict__ flags)
{
    __shared__ bf16 Os[64 * QSTR];
    __shared__ bf16 Wot[64 * QSTR];
    __shared__ float bos[64];

    const int tid = threadIdx.x;
    const int m0  = blockIdx.x * 64;
    const int lane = tid & 63, wave = tid >> 6;
    const int c = lane & 15, quad = lane >> 4;
    const int out_fp32 = flags[0];

    if (tid < 64) bos[tid] = ldx(bo, tid, flags[8]);

    f32x4 acc[4];
    #pragma unroll
    for (int ng = 0; ng < 4; ++ng) acc[ng] = (f32x4){0.f, 0.f, 0.f, 0.f};

    for (int chunk = 0; chunk < 16; ++chunk) {
        const int k0 = chunk * 64;
        __syncthreads();
        #pragma unroll
        for (int i = 0; i < 2; ++i) {
            int item = i * 256 + tid;          // 0..511: row*8 + oct
            int row = item >> 3, oct = item & 7;
            *(bf16x8*)&Os[row * QSTR + oct * 8] =
                *(const bf16x8*)(o + (size_t)(m0 + row) * HID + k0 + oct * 8);
            *(bf16x8*)&Wot[row * QSTR + oct * 8] =
                *(const bf16x8*)(WoT + (size_t)row * HID + k0 + oct * 8);
        }
        __syncthreads();

        bf16x8 a0 = *(const bf16x8*)&Os[(wave * 16 + c) * QSTR + quad * 8];
        bf16x8 a1 = *(const bf16x8*)&Os[(wave * 16 + c) * QSTR + 32 + quad * 8];
        #pragma unroll
        for (int ng = 0; ng < 4; ++ng) {
            bf16x8 b0 = *(const bf16x8*)&Wot[(ng * 16 + c) * QSTR + quad * 8];
            bf16x8 b1 = *(const bf16x8*)&Wot[(ng * 16 + c) * QSTR + 32 + quad * 8];
            acc[ng] = __builtin_amdgcn_mfma_f32_16x16x32_bf16(a0, b0, acc[ng], 0, 0, 0);
            acc[ng] = __builtin_amdgcn_mfma_f32_16x16x32_bf16(a1, b1, acc[ng], 0, 0, 0);
        }
    }

    #pragma unroll
    for (int ng = 0; ng < 4; ++ng) {
        int n = ng * 16 + c;
        float bb_ = bos[n];
        #pragma unroll
        for (int r = 0; r < 4; ++r) {
            int row = m0 + wave * 16 + quad * 4 + r;
            float sum = acc[ng][r] + bb_;
            size_t oidx = (size_t)row * 64 + n;
            if (out_fp32) ((float*)out)[oidx] = sum;
            else          ((bf16*)out)[oidx]  = __float2bfloat16(sum);
        }
    }
}

// ---------------------------------------------------------------------------
extern "C" void kernel_launch(void* const* d_in, const int* in_sizes, int n_in,
                              void* d_out, int out_size, void* d_ws, size_t ws_size,
                              hipStream_t stream)
{
    char* ws = (char*)d_ws;
    const size_t qkv_bytes = (size_t)B * S * HID * sizeof(bf16);  // 16 MiB each
    bf16* qw = (bf16*)(ws);
    bf16* kw = (bf16*)(ws + qkv_bytes);
    bf16* vw = (bf16*)(ws + 2 * qkv_bytes);   // transposed [B][H][D][S]
    bf16* ow = (bf16*)(ws + 3 * qkv_bytes);
    bf16* xb  = (bf16*)(ws + 4 * qkv_bytes);              // 1 MiB
    bf16* WtA = xb + (size_t)B * S * D;                   // 384 KiB
    bf16* WoT = WtA + 3 * HID * 64;                       // 128 KiB
    int* flags = (int*)(WoT + 64 * HID);

    detect_kernel<<<9, 256, 0, stream>>>(d_in[0], d_in[1], d_in[2], d_in[3],
                                         d_in[4], d_in[5], d_in[6], d_in[7],
                                         d_in[8], flags);

    prep_kernel<<<3072, 256, 0, stream>>>(d_in[0], d_in[1], d_in[3], d_in[5],
                                          d_in[7], xb, WtA, WoT, flags);

    qkv_mfma_kernel<<<dim3(B * S / 128, 24), 256, 0, stream>>>(
        xb, WtA, d_in[2], d_in[4], d_in[6], qw, kw, vw, flags);

    flash_mfma_kernel<<<dim3(NT / 2, B * H), 256, 0, stream>>>(qw, kw, vw, ow);

    out_proj_mfma_kernel<<<dim3(B * S / 64), 256, 0, stream>>>(ow, WoT, d_in[8],
                                                               d_out, flags);
}